// Round 2
// baseline (510.050 us; speedup 1.0000x reference)
//
#include <hip/hip_runtime.h>
#include <hip/hip_bf16.h>

// M=K=N=8192. x:[M,K] fp32, weight:[N,K] fp32.
// y[m] = 0.75 * dot(x[m,:], colsum(weight))  -> out is [M,1] fp32 (8192 floats)

#define M_DIM 8192
#define K_DIM 8192
#define N_DIM 8192

#define ROWCHUNKS 128                       // partial vectors
#define ROWS_PER_CHUNK (N_DIM / ROWCHUNKS)  // 64
#define K4 (K_DIM / 4)                      // 2048 float4 columns

// ---------------- Kernel 1a: partial column-sums (no atomics) ----------------
// grid (K4/256 = 8, ROWCHUNKS = 128), block 256.
// Block (bx,by): columns [bx*1024, +1024), rows [by*64, +64).
// Stores its partial [1024]-col slice into partial[by][...].
__global__ __launch_bounds__(256) void colsum_partial(
    const float* __restrict__ w, float* __restrict__ partial) {
    const int col4 = blockIdx.x * 256 + threadIdx.x;   // float4-column index
    const int row0 = blockIdx.y * ROWS_PER_CHUNK;
    const float4* __restrict__ p =
        (const float4*)w + (size_t)row0 * K4 + col4;

    float4 acc = make_float4(0.f, 0.f, 0.f, 0.f);
    #pragma unroll 8
    for (int r = 0; r < ROWS_PER_CHUNK; ++r) {
        float4 v = p[(size_t)r * K4];
        acc.x += v.x; acc.y += v.y; acc.z += v.z; acc.w += v.w;
    }
    ((float4*)partial)[(size_t)blockIdx.y * K4 + col4] = acc;
}

// ---------------- Kernel 1b: fold 128 partials into wcs ----------------
// grid 8, block 256: thread owns one float4 column, sums 128 partials.
__global__ __launch_bounds__(256) void reduce_partials(
    const float* __restrict__ partial, float* __restrict__ wcs) {
    const int col4 = blockIdx.x * 256 + threadIdx.x;
    const float4* __restrict__ p4 = (const float4*)partial;

    float4 acc = make_float4(0.f, 0.f, 0.f, 0.f);
    #pragma unroll 8
    for (int c = 0; c < ROWCHUNKS; ++c) {
        float4 v = p4[(size_t)c * K4 + col4];
        acc.x += v.x; acc.y += v.y; acc.z += v.z; acc.w += v.w;
    }
    ((float4*)wcs)[col4] = acc;
}

// ---------------- Kernel 2: per-row dot with wcs ----------------
// One block (256 threads) per row of x. wcs is 32 KB -> lives in L2/L3.
__global__ __launch_bounds__(256) void rowdot_kernel(
    const float* __restrict__ x, const float* __restrict__ wcs,
    float* __restrict__ y) {
    const int m = blockIdx.x;
    const float4* __restrict__ x4 = (const float4*)(x + (size_t)m * K_DIM);
    const float4* __restrict__ w4 = (const float4*)wcs;

    float acc = 0.f;
    #pragma unroll 8
    for (int i = threadIdx.x; i < K4; i += 256) {
        float4 a = x4[i];
        float4 b = w4[i];
        acc += a.x * b.x + a.y * b.y + a.z * b.z + a.w * b.w;
    }
    // wave-64 shuffle reduction
    #pragma unroll
    for (int off = 32; off > 0; off >>= 1)
        acc += __shfl_down(acc, off, 64);

    __shared__ float sacc[4];
    const int lane = threadIdx.x & 63;
    const int wave = threadIdx.x >> 6;
    if (lane == 0) sacc[wave] = acc;
    __syncthreads();
    if (threadIdx.x == 0) {
        y[m] = 0.75f * (sacc[0] + sacc[1] + sacc[2] + sacc[3]);
    }
}

extern "C" void kernel_launch(void* const* d_in, const int* in_sizes, int n_in,
                              void* d_out, int out_size, void* d_ws, size_t ws_size,
                              hipStream_t stream) {
    const float* x = (const float*)d_in[0];   // [M, K]
    const float* w = (const float*)d_in[1];   // [N, K]
    float* y = (float*)d_out;                 // [M] (== [M,1] flat)

    float* partial = (float*)d_ws;                         // [128][K] = 4 MB
    float* wcs     = (float*)d_ws + (size_t)ROWCHUNKS * K_DIM;  // [K] = 32 KB

    dim3 g1(K4 / 256, ROWCHUNKS);             // 8 x 128 = 1024 blocks
    colsum_partial<<<g1, 256, 0, stream>>>(w, partial);

    reduce_partials<<<K4 / 256, 256, 0, stream>>>(partial, wcs);

    rowdot_kernel<<<M_DIM, 256, 0, stream>>>(x, wcs, y);
}